// Round 3
// baseline (378.561 us; speedup 1.0000x reference)
//
#include <hip/hip_runtime.h>

// P2G quadratic B-spline scatter, MI355X — v10: fp32 LDS atomics in K2.
//
// v8/v9 post-mortem: both FAILED with bit-identical absmax 0.404296875
// despite completely different K1s -> error is deterministic and
// order-independent -> K2's packed 2^22 fixed-point TRUNCATION, not K1
// scrambling. (unsigned)(w*2^22) discards up to 2.4e-7/tap, uncorrelated
// between w and wp; cells with tiny w (~1e-6, from clip-boundary taps)
// amplify via wp/(w+1e-7) to ~0.4. v7's 2^42 dual-u64 was fine (2e-13).
// v10: K2 uses two fp32 LDS arrays + native ds_add_f32. fp32 errors are
// RELATIVE -> wp and w errors scale together -> ratio preserved (same
// numerics as the fp32 jax reference and the proven v1 fallback).
//   K1 (kept from v9): LDS 512-bin histogram, ONE global reservation
//       atomicAdd per non-empty (block,bin) (~0.25M vs v7's 1M), direct
//       store to slots[bin*CAP+gbase+rank] -> each 64B line written by one
//       workgroup (one XCD's L2) -> full-line writebacks.
//   K2: BIN=16, tile 18^3, 2x 23.3KB fp32 LDS, 54M ds_add_f32.
//   K3 (kept): avg 1.30 covering tiles/cell gather + divide.
// Fallback (ws too small or B too large): v1 interleaved global-atomic path.

namespace {

constexpr int   G         = 64;
constexpr int   G3        = G * G * G;            // 262144
constexpr int   BIN       = 16;                   // cells per bin per axis
constexpr int   NBX       = G / BIN;              // 4 bins per axis
constexpr int   BINS_PB   = NBX * NBX * NBX;      // 64 bins per batch
constexpr int   TILE      = BIN + 2;              // 18 (halo -1..16)
constexpr int   TILE3     = TILE * TILE * TILE;   // 5832
constexpr int   CAP       = 2560;                 // slots per bin (avg ~1953)
constexpr int   PPB       = 2048;                 // particles per K1 block
constexpr int   NBINS_MAX = 512;                  // hist size (B<=8)
constexpr float EPS_CLIP  = 1e-5f;
constexpr float EPS_DIV   = 1e-7f;
constexpr float INV_DX    = 64.0f;                // 1/DX (exact pow2)

static_assert((size_t)TILE3 * 2 * 4 < 65536, "K2 LDS over 64KB");

__device__ __forceinline__ float clip01(float v) {
    return fminf(fmaxf(v, EPS_CLIP), 1.0f - EPS_CLIP);
}

__device__ __forceinline__ void bspline_w(float f, float* w) {
    w[0] = 0.5f * (1.0f - f) * (1.0f - f);
    w[1] = 0.75f - (f - 0.5f) * (f - 0.5f);
    w[2] = 0.5f * f * f;
}

// ---------------- K1: per-block reservation + direct line-clustered store -

__global__ void __launch_bounds__(512)
bin_particles_res(const float* __restrict__ pos,
                  const float* __restrict__ prob,
                  const int*   __restrict__ bidx,
                  int*         __restrict__ cnt,    // nbins (<= NBINS_MAX)
                  float4*      __restrict__ slots,  // nbins*CAP
                  int L) {
    __shared__ unsigned int s_hist[NBINS_MAX];
    __shared__ unsigned int s_gbase[NBINS_MAX];  // global base slot per bin

    const int t    = threadIdx.x;
    const int base = blockIdx.x * PPB;

    s_hist[t] = 0u;
    __syncthreads();

    // load + clip + bin + LDS histogram (rank = order within (block,bin))
    float4   pay[PPB / 512];
    int      pbin[PPB / 512];
    unsigned rank[PPB / 512];
#pragma unroll
    for (int k = 0; k < PPB / 512; ++k) {
        int i = base + k * 512 + t;
        pbin[k] = -1;
        if (i < L) {
            float px = clip01(pos[3 * i + 0]);
            float py = clip01(pos[3 * i + 1]);
            float pz = clip01(pos[3 * i + 2]);
            int bx = (int)(px * INV_DX);
            int by = (int)(py * INV_DX);
            int bz = (int)(pz * INV_DX);
            int b  = ((bidx[i] * NBX + (bx >> 4)) * NBX + (by >> 4)) * NBX
                     + (bz >> 4);
            pay[k]  = make_float4(px, py, pz, prob[i]);
            pbin[k] = b;
            rank[k] = atomicAdd(&s_hist[b], 1u);
        }
    }
    __syncthreads();

    // one global reservation atomic per non-empty (block,bin)
    const unsigned c = s_hist[t];
    s_gbase[t] = c ? (unsigned)atomicAdd(&cnt[t], (int)c) : 0u;
    __syncthreads();

    // direct store: this block's slots for bin b occupy [gbase, gbase+c) —
    // each 64B line is written entirely by this block (one XCD's L2).
#pragma unroll
    for (int k = 0; k < PPB / 512; ++k) {
        if (pbin[k] >= 0) {
            unsigned g = s_gbase[pbin[k]] + rank[k];
            if (g < CAP) slots[(size_t)pbin[k] * CAP + g] = pay[k];
        }
    }
}

// ---------------- K2: per-bin LDS tile, fp32 ds_add_f32 -------------------

__global__ void __launch_bounds__(512)
accumulate_bins(const float4* __restrict__ slots,
                const int*    __restrict__ cnt,
                float2*       __restrict__ tiles) {   // nbins*TILE3
    __shared__ float t_w[TILE3];
    __shared__ float t_wp[TILE3];
    const int bin = blockIdx.x;
    const int tid = threadIdx.x;

    for (int j = tid; j < TILE3; j += 512) { t_w[j] = 0.f; t_wp[j] = 0.f; }
    __syncthreads();

    const int n = min(cnt[bin], CAP);
    // bin = ((batch*4 + bbx)*4 + bby)*4 + bbz
    const int bx0 = ((bin >> 4) & 3) * BIN;
    const int by0 = ((bin >> 2) & 3) * BIN;
    const int bz0 = (bin & 3) * BIN;
    const float4* sbase = slots + (size_t)bin * CAP;

    for (int s = tid; s < n; s += 512) {
        float4 r = sbase[s];                         // coalesced 16B load
        float xp = r.x * INV_DX;                     // pos pre-clipped in K1
        float yp = r.y * INV_DX;
        float zp = r.z * INV_DX;
        int bx = (int)xp, by = (int)yp, bz = (int)zp;
        // defensive: an anomalous slot must never index LDS out of bounds
        int l0x = bx - bx0, l0y = by - by0, l0z = bz - bz0;
        if (((l0x | l0y | l0z) & ~15) != 0) continue;
        float wx[3], wy[3], wz[3];
        bspline_w(xp - (float)bx, wx);
        bspline_w(yp - (float)by, wy);
        bspline_w(zp - (float)bz, wz);
        float p = r.w;
#pragma unroll
        for (int a = 0; a < 3; ++a) {
            int ix = (l0x + a) * TILE;
#pragma unroll
            for (int cc = 0; cc < 3; ++cc) {
                int ixy = (ix + l0y + cc) * TILE;
                float wxy = wx[a] * wy[cc];
#pragma unroll
                for (int e = 0; e < 3; ++e) {
                    float w  = wxy * wz[e];
                    int  ci  = ixy + l0z + e;
                    atomicAdd(&t_w[ci],  w);       // native ds_add_f32
                    atomicAdd(&t_wp[ci], w * p);
                }
            }
        }
    }
    __syncthreads();

    float2* gt = tiles + (size_t)bin * TILE3;
    for (int j = tid; j < TILE3; j += 512) {
        gt[j] = make_float2(t_w[j], t_wp[j]);
    }
}

// ---------------- K3: gather overlapping tiles + divide -------------------

__global__ void finalize_tiles(const float2* __restrict__ tiles,
                               float*        __restrict__ out,
                               int total) {
    int c = blockIdx.x * blockDim.x + threadIdx.x;
    if (c >= total) return;
    int cz = c & 63, cy = (c >> 6) & 63, cx = (c >> 12) & 63, b = c >> 18;
    int bx = cx >> 4, mx = cx & 15;
    int by = cy >> 4, my = cy & 15;
    int bz = cz >> 4, mz = cz & 15;

    // per-axis list of (bin coord, tile-local index) covering this cell
    int xb[2], xl[2], nx = 1; xb[0] = bx; xl[0] = mx + 1;
    if (mx == 0 && bx > 0)            { xb[1] = bx - 1; xl[1] = TILE - 1; nx = 2; }
    else if (mx == 15 && bx < NBX - 1){ xb[1] = bx + 1; xl[1] = 0;        nx = 2; }
    int yb[2], yl[2], ny = 1; yb[0] = by; yl[0] = my + 1;
    if (my == 0 && by > 0)            { yb[1] = by - 1; yl[1] = TILE - 1; ny = 2; }
    else if (my == 15 && by < NBX - 1){ yb[1] = by + 1; yl[1] = 0;        ny = 2; }
    int zb[2], zl[2], nz = 1; zb[0] = bz; zl[0] = mz + 1;
    if (mz == 0 && bz > 0)            { zb[1] = bz - 1; zl[1] = TILE - 1; nz = 2; }
    else if (mz == 15 && bz < NBX - 1){ zb[1] = bz + 1; zl[1] = 0;        nz = 2; }

    float w = 0.f, wp = 0.f;
    for (int i = 0; i < nx; ++i)
        for (int j = 0; j < ny; ++j)
            for (int k = 0; k < nz; ++k) {
                int bin = ((b * NBX + xb[i]) * NBX + yb[j]) * NBX + zb[k];
                float2 v = tiles[(size_t)bin * TILE3
                                 + (xl[i] * TILE + yl[j]) * TILE + zl[k]];
                w += v.x; wp += v.y;
            }
    out[c] = wp / (w + EPS_DIV);
}

// ---------------- fallback kernels (v1) -----------------------------------

__global__ void scatter_interleaved(const float* __restrict__ pos,
                                    const float* __restrict__ prob,
                                    const int*   __restrict__ bidx,
                                    float2*      __restrict__ grid,
                                    int L) {
    int i = blockIdx.x * blockDim.x + threadIdx.x;
    if (i >= L) return;
    float xp = clip01(pos[3 * i + 0]) * INV_DX;
    float yp = clip01(pos[3 * i + 1]) * INV_DX;
    float zp = clip01(pos[3 * i + 2]) * INV_DX;
    int bx = (int)xp, by = (int)yp, bz = (int)zp;
    float wx[3], wy[3], wz[3];
    bspline_w(xp - (float)bx, wx);
    bspline_w(yp - (float)by, wy);
    bspline_w(zp - (float)bz, wz);
    float p = prob[i];
    float2* gbase = grid + (size_t)bidx[i] * G3;
#pragma unroll
    for (int a = 0; a < 3; ++a) {
        int tx = bx + a - 1;
        if (tx < 0 || tx >= G) continue;
#pragma unroll
        for (int c = 0; c < 3; ++c) {
            int ty = by + c - 1;
            if (ty < 0 || ty >= G) continue;
            float wxy = wx[a] * wy[c];
            int rowoff = (tx * G + ty) * G;
#pragma unroll
            for (int e = 0; e < 3; ++e) {
                int tz = bz + e - 1;
                if (tz < 0 || tz >= G) continue;
                float w = wxy * wz[e];
                float2* cell = gbase + rowoff + tz;
                atomicAdd(&cell->x, w);
                atomicAdd(&cell->y, w * p);
            }
        }
    }
}

__global__ void finalize_interleaved(const float2* __restrict__ grid,
                                     float* __restrict__ out, int n) {
    int i = blockIdx.x * blockDim.x + threadIdx.x;
    if (i >= n) return;
    float2 c = grid[i];
    out[i] = c.y / (c.x + EPS_DIV);
}

} // anonymous namespace

extern "C" void kernel_launch(void* const* d_in, const int* in_sizes, int n_in,
                              void* d_out, int out_size, void* d_ws, size_t ws_size,
                              hipStream_t stream) {
    const float* pos  = (const float*)d_in[0];
    const float* prob = (const float*)d_in[1];
    const int*   bidx = (const int*)d_in[2];
    float* out = (float*)d_out;

    const int L = in_sizes[1];            // prob has L elements
    const int B = out_size / G3;          // out_size == B * G3
    const int nbins = B * BINS_PB;

    const int threads = 256;
    const int k1blocks = (L + PPB - 1) / PPB;
    const int pblocks  = (L + threads - 1) / threads;
    const int fblocks  = (out_size + threads - 1) / threads;

    // ws layout: [tiles: nbins*TILE3*8B][slots: nbins*CAP*16B][cnt: nbins*4B]
    const size_t tiles_bytes = (size_t)nbins * TILE3 * sizeof(float2);
    const size_t slots_bytes = (size_t)nbins * CAP * sizeof(float4);
    const size_t cnt_bytes   = (size_t)nbins * sizeof(int);
    const size_t need        = tiles_bytes + slots_bytes + cnt_bytes;

    if (ws_size >= need && nbins <= NBINS_MAX) {
        float2* tiles = (float2*)d_ws;
        float4* slots = (float4*)((char*)d_ws + tiles_bytes);
        int*    cnt   = (int*)((char*)d_ws + tiles_bytes + slots_bytes);

        hipMemsetAsync(cnt, 0, cnt_bytes, stream);
        bin_particles_res<<<k1blocks, 512, 0, stream>>>(pos, prob, bidx,
                                                        cnt, slots, L);
        accumulate_bins<<<nbins, 512, 0, stream>>>(slots, cnt, tiles);
        finalize_tiles<<<fblocks, threads, 0, stream>>>(tiles, out, out_size);
    } else if (ws_size >= (size_t)out_size * 2 * sizeof(float)) {
        // v1 fallback: interleaved global-atomic scatter
        float2* grid = (float2*)d_ws;
        hipMemsetAsync(d_ws, 0, (size_t)out_size * 2 * sizeof(float), stream);
        scatter_interleaved<<<pblocks, threads, 0, stream>>>(pos, prob, bidx, grid, L);
        finalize_interleaved<<<fblocks, threads, 0, stream>>>(grid, out, out_size);
    }
}

// Round 4
// 122.361 us; speedup vs baseline: 3.0938x; 3.0938x over previous
//
#include <hip/hip_runtime.h>

// P2G quadratic B-spline scatter, MI355X — v11: u64 fixed-point restored,
// two-pass K2, counting-sort K1 restored.
//
// History of evidence:
//  v7  (182 us, PASS): K1 scatter-wall 76 us; K2 BIN=8, 2x ds_add_u64 @2^42
//      fixed point -> absmax 0.0039. Integer LDS atomics PROVEN fast+accurate.
//  v8/v9 (FAIL, bit-identical 0.4043): K2 packed 2^22 truncation, NOT K1 —
//      identical error across two different K1s exonerates the counting sort.
//  v10 (378 us, PASS): fp32 ds atomics in K2 = 285 us with VALU 1.2%, bank
//      conflicts 0, HBM 1.4% — fp32 shared atomicAdd is ~4x slower than
//      ds_add_u64 path AND grid was thin (512 blocks, 16 waves/CU). K1
//      reservation-only kept scattered per-wave stores -> still ~75 us.
// v11:
//  K1 = v8's full counting sort (histogram -> scan -> physical LDS reorder ->
//       linear drain): wave stores hit consecutive slots (~16 line-segments
//       per wave vs 64 scattered). 0.25M global reservation atomics.
//  K2 = two passes per bin (grid nbins*2): pass A sums w, pass B sums w*p,
//       each into ONE u64 tile @2^42 (46.7 KB LDS, 3 blocks/CU, 24 waves).
//       Same 54M total LDS atomics as v7, same numerics as v7.
//  K3 = SoA gather (tiles_w, tiles_wp) + divide.
// Fallback (ws too small or B too large): v1 interleaved global-atomic path.

namespace {

constexpr int   G         = 64;
constexpr int   G3        = G * G * G;            // 262144
constexpr int   BIN       = 16;                   // cells per bin per axis
constexpr int   NBX       = G / BIN;              // 4 bins per axis
constexpr int   BINS_PB   = NBX * NBX * NBX;      // 64 bins per batch
constexpr int   TILE      = BIN + 2;              // 18 (halo -1..16)
constexpr int   TILE3     = TILE * TILE * TILE;   // 5832
constexpr int   CAP       = 2560;                 // slots per bin (avg ~1953)
constexpr int   PPB       = 2048;                 // particles per K1 block
constexpr int   NBINS_MAX = 512;                  // hist size (B<=8)
constexpr float EPS_CLIP  = 1e-5f;
constexpr float EPS_DIV   = 1e-7f;
constexpr float INV_DX    = 64.0f;                // 1/DX (exact pow2)
constexpr float FXS       = 4398046511104.0f;     // 2^42 fixed-point scale
constexpr float INV_FXS   = 1.0f / FXS;

static_assert((size_t)TILE3 * 8 < 65536, "K2 LDS over 64KB");

__device__ __forceinline__ float clip01(float v) {
    return fminf(fmaxf(v, EPS_CLIP), 1.0f - EPS_CLIP);
}

__device__ __forceinline__ void bspline_w(float f, float* w) {
    w[0] = 0.5f * (1.0f - f) * (1.0f - f);
    w[1] = 0.75f - (f - 0.5f) * (f - 0.5f);
    w[2] = 0.5f * f * f;
}

// ---------------- K1: block counting sort + linear coalesced drain --------

__global__ void __launch_bounds__(512)
bin_sort_mat(const float* __restrict__ pos,
             const float* __restrict__ prob,
             const int*   __restrict__ bidx,
             int*         __restrict__ cnt,    // nbins (<= NBINS_MAX)
             float4*      __restrict__ slots,  // nbins*CAP
             int L) {
    __shared__ unsigned int   s_hist[NBINS_MAX];
    __shared__ unsigned int   s_incl[NBINS_MAX];   // inclusive scan of hist
    __shared__ unsigned int   s_gbase[NBINS_MAX];  // global base slot per bin
    __shared__ float4         s_pay[PPB];          // 32 KB sorted payload
    __shared__ unsigned short s_bin[PPB];          // bin id per sorted slot

    const int t    = threadIdx.x;
    const int base = blockIdx.x * PPB;
    const int np   = min(PPB, L - base);

    s_hist[t] = 0u;
    __syncthreads();

    // load + clip + bin + LDS histogram (rank = order within (block,bin))
    float4   pay[PPB / 512];
    int      pbin[PPB / 512];
    unsigned rank[PPB / 512];
#pragma unroll
    for (int k = 0; k < PPB / 512; ++k) {
        int i = base + k * 512 + t;
        pbin[k] = -1;
        if (i < L) {
            float px = clip01(pos[3 * i + 0]);
            float py = clip01(pos[3 * i + 1]);
            float pz = clip01(pos[3 * i + 2]);
            int bx = (int)(px * INV_DX);
            int by = (int)(py * INV_DX);
            int bz = (int)(pz * INV_DX);
            int b  = ((bidx[i] * NBX + (bx >> 4)) * NBX + (by >> 4)) * NBX
                     + (bz >> 4);
            pay[k]  = make_float4(px, py, pz, prob[i]);
            pbin[k] = b;
            rank[k] = atomicAdd(&s_hist[b], 1u);
        }
    }
    __syncthreads();

    // one global reservation atomic per non-empty (block,bin)
    const unsigned c = s_hist[t];
    s_gbase[t] = c ? (unsigned)atomicAdd(&cnt[t], (int)c) : 0u;

    // inclusive Hillis-Steele scan, 512 entries, 1/thread
    s_incl[t] = c;
    __syncthreads();
#pragma unroll
    for (int st = 1; st < NBINS_MAX; st <<= 1) {
        unsigned v = (t >= st) ? s_incl[t - st] : 0u;
        __syncthreads();
        s_incl[t] += v;
        __syncthreads();
    }

    // physical reorder into LDS (sorted position = excl[bin] + rank)
#pragma unroll
    for (int k = 0; k < PPB / 512; ++k) {
        if (pbin[k] >= 0) {
            int b = pbin[k];
            unsigned sp = s_incl[b] - s_hist[b] + rank[k];
            s_pay[sp] = pay[k];
            s_bin[sp] = (unsigned short)b;
        }
    }
    __syncthreads();

    // linear drain: consecutive sorted particles -> consecutive slot addrs
    for (int j = t; j < np; j += 512) {
        int b = s_bin[j];
        unsigned local = (unsigned)j - (s_incl[b] - s_hist[b]);
        unsigned g = s_gbase[b] + local;
        if (g < CAP) slots[(size_t)b * CAP + g] = s_pay[j];
    }
}

// ---------------- K2: per-bin u64 tile, two passes (w, then w*p) ----------

__global__ void __launch_bounds__(512)
accumulate_bins_pass(const float4* __restrict__ slots,
                     const int*    __restrict__ cnt,
                     float*        __restrict__ tiles_w,    // nbins*TILE3
                     float*        __restrict__ tiles_wp) { // nbins*TILE3
    __shared__ unsigned long long t_acc[TILE3];   // 46.7 KB
    const int bin   = blockIdx.x >> 1;
    const int which = blockIdx.x & 1;             // 0: w, 1: w*p
    const int tid   = threadIdx.x;

    for (int j = tid; j < TILE3; j += 512) t_acc[j] = 0ull;
    __syncthreads();

    const int n = min(cnt[bin], CAP);
    // bin = ((batch*4 + bbx)*4 + bby)*4 + bbz
    const int bx0 = ((bin >> 4) & 3) * BIN;
    const int by0 = ((bin >> 2) & 3) * BIN;
    const int bz0 = (bin & 3) * BIN;
    const float4* sbase = slots + (size_t)bin * CAP;

    for (int s = tid; s < n; s += 512) {
        float4 r = sbase[s];                         // coalesced 16B load
        float xp = r.x * INV_DX;                     // pos pre-clipped in K1
        float yp = r.y * INV_DX;
        float zp = r.z * INV_DX;
        int bx = (int)xp, by = (int)yp, bz = (int)zp;
        // defensive: an anomalous slot must never index LDS out of bounds
        int l0x = bx - bx0, l0y = by - by0, l0z = bz - bz0;
        if (((l0x | l0y | l0z) & ~15) != 0) continue;
        float wx[3], wy[3], wz[3];
        bspline_w(xp - (float)bx, wx);
        bspline_w(yp - (float)by, wy);
        bspline_w(zp - (float)bz, wz);
        float p = which ? r.w : 1.0f;                // unify both passes
#pragma unroll
        for (int a = 0; a < 3; ++a) {
            int ix = (l0x + a) * TILE;
#pragma unroll
            for (int cc = 0; cc < 3; ++cc) {
                int ixy = (ix + l0y + cc) * TILE;
                float wxy = wx[a] * wy[cc] * p;
#pragma unroll
                for (int e = 0; e < 3; ++e) {
                    float v = wxy * wz[e];
                    atomicAdd(&t_acc[ixy + l0z + e],
                              (unsigned long long)(v * FXS));
                }
            }
        }
    }
    __syncthreads();

    float* gt = (which ? tiles_wp : tiles_w) + (size_t)bin * TILE3;
    for (int j = tid; j < TILE3; j += 512) {
        gt[j] = (float)t_acc[j] * INV_FXS;
    }
}

// ---------------- K3: gather overlapping tiles + divide -------------------

__global__ void finalize_tiles(const float* __restrict__ tiles_w,
                               const float* __restrict__ tiles_wp,
                               float*       __restrict__ out,
                               int total) {
    int c = blockIdx.x * blockDim.x + threadIdx.x;
    if (c >= total) return;
    int cz = c & 63, cy = (c >> 6) & 63, cx = (c >> 12) & 63, b = c >> 18;
    int bx = cx >> 4, mx = cx & 15;
    int by = cy >> 4, my = cy & 15;
    int bz = cz >> 4, mz = cz & 15;

    // per-axis list of (bin coord, tile-local index) covering this cell
    int xb[2], xl[2], nx = 1; xb[0] = bx; xl[0] = mx + 1;
    if (mx == 0 && bx > 0)            { xb[1] = bx - 1; xl[1] = TILE - 1; nx = 2; }
    else if (mx == 15 && bx < NBX - 1){ xb[1] = bx + 1; xl[1] = 0;        nx = 2; }
    int yb[2], yl[2], ny = 1; yb[0] = by; yl[0] = my + 1;
    if (my == 0 && by > 0)            { yb[1] = by - 1; yl[1] = TILE - 1; ny = 2; }
    else if (my == 15 && by < NBX - 1){ yb[1] = by + 1; yl[1] = 0;        ny = 2; }
    int zb[2], zl[2], nz = 1; zb[0] = bz; zl[0] = mz + 1;
    if (mz == 0 && bz > 0)            { zb[1] = bz - 1; zl[1] = TILE - 1; nz = 2; }
    else if (mz == 15 && bz < NBX - 1){ zb[1] = bz + 1; zl[1] = 0;        nz = 2; }

    float w = 0.f, wp = 0.f;
    for (int i = 0; i < nx; ++i)
        for (int j = 0; j < ny; ++j)
            for (int k = 0; k < nz; ++k) {
                int bin = ((b * NBX + xb[i]) * NBX + yb[j]) * NBX + zb[k];
                size_t idx = (size_t)bin * TILE3
                             + (xl[i] * TILE + yl[j]) * TILE + zl[k];
                w  += tiles_w[idx];
                wp += tiles_wp[idx];
            }
    out[c] = wp / (w + EPS_DIV);
}

// ---------------- fallback kernels (v1) -----------------------------------

__global__ void scatter_interleaved(const float* __restrict__ pos,
                                    const float* __restrict__ prob,
                                    const int*   __restrict__ bidx,
                                    float2*      __restrict__ grid,
                                    int L) {
    int i = blockIdx.x * blockDim.x + threadIdx.x;
    if (i >= L) return;
    float xp = clip01(pos[3 * i + 0]) * INV_DX;
    float yp = clip01(pos[3 * i + 1]) * INV_DX;
    float zp = clip01(pos[3 * i + 2]) * INV_DX;
    int bx = (int)xp, by = (int)yp, bz = (int)zp;
    float wx[3], wy[3], wz[3];
    bspline_w(xp - (float)bx, wx);
    bspline_w(yp - (float)by, wy);
    bspline_w(zp - (float)bz, wz);
    float p = prob[i];
    float2* gbase = grid + (size_t)bidx[i] * G3;
#pragma unroll
    for (int a = 0; a < 3; ++a) {
        int tx = bx + a - 1;
        if (tx < 0 || tx >= G) continue;
#pragma unroll
        for (int c = 0; c < 3; ++c) {
            int ty = by + c - 1;
            if (ty < 0 || ty >= G) continue;
            float wxy = wx[a] * wy[c];
            int rowoff = (tx * G + ty) * G;
#pragma unroll
            for (int e = 0; e < 3; ++e) {
                int tz = bz + e - 1;
                if (tz < 0 || tz >= G) continue;
                float w = wxy * wz[e];
                float2* cell = gbase + rowoff + tz;
                atomicAdd(&cell->x, w);
                atomicAdd(&cell->y, w * p);
            }
        }
    }
}

__global__ void finalize_interleaved(const float2* __restrict__ grid,
                                     float* __restrict__ out, int n) {
    int i = blockIdx.x * blockDim.x + threadIdx.x;
    if (i >= n) return;
    float2 c = grid[i];
    out[i] = c.y / (c.x + EPS_DIV);
}

} // anonymous namespace

extern "C" void kernel_launch(void* const* d_in, const int* in_sizes, int n_in,
                              void* d_out, int out_size, void* d_ws, size_t ws_size,
                              hipStream_t stream) {
    const float* pos  = (const float*)d_in[0];
    const float* prob = (const float*)d_in[1];
    const int*   bidx = (const int*)d_in[2];
    float* out = (float*)d_out;

    const int L = in_sizes[1];            // prob has L elements
    const int B = out_size / G3;          // out_size == B * G3
    const int nbins = B * BINS_PB;

    const int threads = 256;
    const int k1blocks = (L + PPB - 1) / PPB;
    const int pblocks  = (L + threads - 1) / threads;
    const int fblocks  = (out_size + threads - 1) / threads;

    // ws: [tiles_w: nbins*TILE3*4B][tiles_wp: same][slots: nbins*CAP*16B][cnt]
    const size_t tilesw_bytes = (size_t)nbins * TILE3 * sizeof(float);
    const size_t slots_bytes  = (size_t)nbins * CAP * sizeof(float4);
    const size_t cnt_bytes    = (size_t)nbins * sizeof(int);
    const size_t need         = 2 * tilesw_bytes + slots_bytes + cnt_bytes;

    if (ws_size >= need && nbins <= NBINS_MAX) {
        float*  tiles_w  = (float*)d_ws;
        float*  tiles_wp = (float*)((char*)d_ws + tilesw_bytes);
        float4* slots    = (float4*)((char*)d_ws + 2 * tilesw_bytes);
        int*    cnt      = (int*)((char*)d_ws + 2 * tilesw_bytes + slots_bytes);

        hipMemsetAsync(cnt, 0, cnt_bytes, stream);
        bin_sort_mat<<<k1blocks, 512, 0, stream>>>(pos, prob, bidx,
                                                   cnt, slots, L);
        accumulate_bins_pass<<<nbins * 2, 512, 0, stream>>>(slots, cnt,
                                                            tiles_w, tiles_wp);
        finalize_tiles<<<fblocks, threads, 0, stream>>>(tiles_w, tiles_wp,
                                                        out, out_size);
    } else if (ws_size >= (size_t)out_size * 2 * sizeof(float)) {
        // v1 fallback: interleaved global-atomic scatter
        float2* grid = (float2*)d_ws;
        hipMemsetAsync(d_ws, 0, (size_t)out_size * 2 * sizeof(float), stream);
        scatter_interleaved<<<pblocks, threads, 0, stream>>>(pos, prob, bidx, grid, L);
        finalize_interleaved<<<fblocks, threads, 0, stream>>>(grid, out, out_size);
    }
}